// Round 1
// baseline (828.551 us; speedup 1.0000x reference)
//
#include <hip/hip_runtime.h>
#include <stdint.h>

// CAN_Layer reduces exactly to: out[:, :2048] = out[:, 2048:] =
//   0.5 * (protein @ Wv_p + drug @ Wv_d)
// because seq-len is 1 -> softmax over a singleton axis == 1 -> attention
// is the identity over V. Q/K weights are dead.
//
// Strategy: bf16 MFMA GEMM, M=16384 N=2048 K=4096 (K = [protein|drug]).
// Pass 1a: cast+transpose Wv_p/Wv_d -> Wt bf16 [2048][4096] (B^T layout).
// Pass 1b: cast protein|drug -> Abf bf16 [16384][4096].
// Pass 2:  m97-structure GEMM: 128x128 tile, BK=64, global_load_lds(16B),
//          mfma_f32_16x16x32_bf16, 4x4 acc per wave.

typedef __attribute__((ext_vector_type(8))) short short8;
typedef __attribute__((ext_vector_type(4))) float float4v;
typedef __attribute__((ext_vector_type(2))) unsigned int uint2v;

typedef const __attribute__((address_space(1))) unsigned int* gp_t;
typedef __attribute__((address_space(3))) unsigned int* lp_t;

#define M_DIM 16384
#define N_DIM 2048
#define K_DIM 4096
#define OUT_LD 4096

static __device__ __forceinline__ unsigned int pack_bf16x2(float x, float y) {
  // round-half-up to bf16, pack two: [bf16(x) | bf16(y)<<16] via v_perm_b32
  union { float f; unsigned int u; } a, b;
  a.f = x; b.f = y;
  unsigned int ua = a.u + 0x8000u;
  unsigned int ub = b.u + 0x8000u;
  return __builtin_amdgcn_perm(ub, ua, 0x07060302u);
}

static __device__ __forceinline__ unsigned short f2bf(float x) {
  union { float f; unsigned int u; } a; a.f = x;
  return (unsigned short)((a.u + 0x8000u) >> 16);
}

// ---- Pass 1a: Wt[n][k] = bf16(W[k][n]), W = Wv_p (k<2048) else Wv_d ----
__global__ __launch_bounds__(256)
void prep_wt(const float* __restrict__ Wp, const float* __restrict__ Wd,
             unsigned short* __restrict__ Wt) {
  __shared__ float tile[32][33];
  const int k0 = blockIdx.x * 32;   // 0..4095 (128 tiles)
  const int n0 = blockIdx.y * 32;   // 0..2047 (64 tiles)
  const int tx = threadIdx.x;       // 0..31
  const int ty = threadIdx.y;       // 0..7
  const float* W = (k0 < 2048) ? Wp : Wd;
  const int kk0 = (k0 < 2048) ? k0 : k0 - 2048;
#pragma unroll
  for (int i = 0; i < 4; ++i) {
    int r = ty * 4 + i;
    tile[r][tx] = W[(size_t)(kk0 + r) * 2048 + n0 + tx];
  }
  __syncthreads();
#pragma unroll
  for (int i = 0; i < 4; ++i) {
    int r = ty * 4 + i;
    Wt[(size_t)(n0 + r) * (size_t)K_DIM + k0 + tx] = f2bf(tile[tx][r]);
  }
}

// ---- Pass 1b: Abf[m][k] = bf16([protein | drug][m][k]), stored as uint pairs
__global__ __launch_bounds__(256)
void cast_a(const float* __restrict__ P, const float* __restrict__ Dg,
            unsigned int* __restrict__ Abf) {
  int idx = blockIdx.x * 256 + threadIdx.x;  // 16.8M threads, 4 floats each
  int row = idx >> 10;                       // 1024 float4 per 4096-col row
  int j = (idx & 1023) << 2;
  const float* src = (j < 2048) ? (P + (size_t)row * 2048 + j)
                                : (Dg + (size_t)row * 2048 + (j - 2048));
  float4v v = *(const float4v*)src;
  uint2v o;
  o.x = pack_bf16x2(v.x, v.y);
  o.y = pack_bf16x2(v.z, v.w);
  *(uint2v*)(Abf + (size_t)row * 2048 + (j >> 1)) = o;
}

// ---- Pass 2: GEMM. ABF=true: A from bf16 ws via global_load_lds.
//              ABF=false: A from fp32 protein/drug, cvt during staging. ----
template <bool ABF>
__global__ __launch_bounds__(256)
void gemm_k(const unsigned int* __restrict__ Abf,
            const float* __restrict__ Ap, const float* __restrict__ Ad,
            const unsigned short* __restrict__ Wt,
            float* __restrict__ out) {
  __shared__ unsigned short As[128 * 64];  // [m][k] bf16, 128B rows
  __shared__ unsigned short Bs[128 * 64];  // [n][k] bf16 (B^T), 128B rows

  const int t = threadIdx.x;
  const int bx = blockIdx.x;
  const int tn = bx & 15, tm = bx >> 4;    // N-fastest: 16 blocks share A stripe
  const int m0 = tm << 7, n0 = tn << 7;
  const int w = t >> 6, l = t & 63;
  const int wm = w & 1, wn = w >> 1;       // 2x2 wave grid, 64x64 per wave
  const int lr = l & 15, q = l >> 4;

  const int rB = t >> 3;                   // staging row 0..31 per issue
  const int kB = (t & 7) * 8;              // staging k offset (8 bf16 = 16B)

  float4v acc[4][4];
#pragma unroll
  for (int i = 0; i < 4; ++i)
#pragma unroll
    for (int j = 0; j < 4; ++j)
      acc[i][j] = (float4v){0.f, 0.f, 0.f, 0.f};

  for (int k0 = 0; k0 < K_DIM; k0 += 64) {
    // stage B tile (always bf16 Wt, direct-to-LDS 16B)
#pragma unroll
    for (int i = 0; i < 4; ++i) {
      const unsigned short* g =
          Wt + (size_t)(n0 + i * 32 + rB) * (size_t)K_DIM + (k0 + kB);
      __builtin_amdgcn_global_load_lds((gp_t)(const void*)g,
                                       (lp_t)&Bs[i * 2048 + w * 512], 16, 0, 0);
    }
    if constexpr (ABF) {
#pragma unroll
      for (int i = 0; i < 4; ++i) {
        const unsigned int* g =
            Abf + ((size_t)(m0 + i * 32 + rB) * (size_t)K_DIM + (k0 + kB)) / 2;
        __builtin_amdgcn_global_load_lds((gp_t)(const void*)g,
                                         (lp_t)&As[i * 2048 + w * 512], 16, 0, 0);
      }
    } else {
      const float* base;
      int kk;
      if (k0 < 2048) { base = Ap; kk = k0; } else { base = Ad; kk = k0 - 2048; }
      const int rA = t >> 4;          // 0..15
      const int cA = (t & 15) * 4;    // 0..60
#pragma unroll
      for (int i = 0; i < 8; ++i) {
        int m = i * 16 + rA;
        float4v v = *(const float4v*)(base + (size_t)(m0 + m) * 2048 + kk + cA);
        uint2v o;
        o.x = pack_bf16x2(v.x, v.y);
        o.y = pack_bf16x2(v.z, v.w);
        *(uint2v*)&As[m * 64 + cA] = o;
      }
    }
    __syncthreads();

#pragma unroll
    for (int ks = 0; ks < 2; ++ks) {
      short8 af[4], bfr[4];
#pragma unroll
      for (int i = 0; i < 4; ++i) {
        af[i]  = *(const short8*)&As[(wm * 64 + i * 16 + lr) * 64 + ks * 32 + q * 8];
        bfr[i] = *(const short8*)&Bs[(wn * 64 + i * 16 + lr) * 64 + ks * 32 + q * 8];
      }
#pragma unroll
      for (int i = 0; i < 4; ++i)
#pragma unroll
        for (int j = 0; j < 4; ++j)
          acc[i][j] = __builtin_amdgcn_mfma_f32_16x16x32_bf16(af[i], bfr[j],
                                                              acc[i][j], 0, 0, 0);
    }
    __syncthreads();
  }

  // epilogue: C/D layout col=lane&15, row=quad*4+reg; write both halves
#pragma unroll
  for (int i = 0; i < 4; ++i) {
    const int r0 = m0 + wm * 64 + i * 16 + q * 4;
#pragma unroll
    for (int j = 0; j < 4; ++j) {
      const int c = n0 + wn * 64 + j * 16 + lr;
#pragma unroll
      for (int r = 0; r < 4; ++r) {
        float v = acc[i][j][r] * 0.5f;
        size_t o = (size_t)(r0 + r) * (size_t)OUT_LD + c;
        out[o] = v;
        out[o + 2048] = v;
      }
    }
  }
}

// ---- insurance fallback (no usable ws): fp32 LDS-tiled vector GEMM ----
__global__ __launch_bounds__(256)
void gemm_fallback(const float* __restrict__ P, const float* __restrict__ Dg,
                   const float* __restrict__ Wp, const float* __restrict__ Wd,
                   float* __restrict__ out) {
  __shared__ float Asf[64][17];
  __shared__ float Bsf[16][65];
  const int bx = blockIdx.x;  // 32 N-tiles
  const int by = blockIdx.y;  // 256 M-tiles
  const int t = threadIdx.x;
  const int tc = t & 15, trw = t >> 4;
  const int m0 = by * 64, n0 = bx * 64;
  float accf[4][4] = {};
  for (int k0 = 0; k0 < 4096; k0 += 16) {
    const float* Asrc = (k0 < 2048) ? P : Dg;
    const float* Bsrc = (k0 < 2048) ? Wp : Wd;
    const int kk = k0 & 2047;
#pragma unroll
    for (int i = 0; i < 4; ++i) {
      int r = i * 16 + trw;
      Asf[r][tc] = Asrc[(size_t)(m0 + r) * 2048 + kk + tc];
    }
#pragma unroll
    for (int i = 0; i < 4; ++i) {
      int r = i * 4 + (t >> 6);
      int c = t & 63;
      Bsf[r][c] = Bsrc[(size_t)(kk + r) * 2048 + n0 + c];
    }
    __syncthreads();
#pragma unroll
    for (int k2 = 0; k2 < 16; ++k2) {
      float a[4], b[4];
#pragma unroll
      for (int i = 0; i < 4; ++i) a[i] = Asf[trw * 4 + i][k2];
#pragma unroll
      for (int j = 0; j < 4; ++j) b[j] = Bsf[k2][tc * 4 + j];
#pragma unroll
      for (int i = 0; i < 4; ++i)
#pragma unroll
        for (int j = 0; j < 4; ++j) accf[i][j] += a[i] * b[j];
    }
    __syncthreads();
  }
#pragma unroll
  for (int i = 0; i < 4; ++i)
#pragma unroll
    for (int j = 0; j < 4; ++j) {
      float v = accf[i][j] * 0.5f;
      size_t o = (size_t)(m0 + trw * 4 + i) * 4096 + n0 + tc * 4 + j;
      out[o] = v;
      out[o + 2048] = v;
    }
}

extern "C" void kernel_launch(void* const* d_in, const int* in_sizes, int n_in,
                              void* d_out, int out_size, void* d_ws, size_t ws_size,
                              hipStream_t stream) {
  // setup_inputs order: protein, drug, mask_prot, mask_drug,
  //                     Wq_p, Wk_p, Wv_p, Wq_d, Wk_d, Wv_d
  const float* protein = (const float*)d_in[0];
  const float* drug    = (const float*)d_in[1];
  const float* Wv_p    = (const float*)d_in[6];
  const float* Wv_d    = (const float*)d_in[9];
  float* out = (float*)d_out;

  const size_t wt_bytes = (size_t)N_DIM * K_DIM * sizeof(unsigned short);  // 16.8 MB
  const size_t a_bytes  = (size_t)M_DIM * K_DIM * sizeof(unsigned short);  // 134 MB

  if (ws_size >= wt_bytes) {
    unsigned short* Wt = (unsigned short*)d_ws;
    prep_wt<<<dim3(128, 64), dim3(32, 8), 0, stream>>>(Wv_p, Wv_d, Wt);
    if (ws_size >= wt_bytes + a_bytes) {
      unsigned int* Abf = (unsigned int*)((char*)d_ws + wt_bytes);
      cast_a<<<65536, 256, 0, stream>>>(protein, drug, Abf);
      gemm_k<true><<<2048, 256, 0, stream>>>(Abf, nullptr, nullptr, Wt, out);
    } else {
      gemm_k<false><<<2048, 256, 0, stream>>>(nullptr, protein, drug, Wt, out);
    }
  } else {
    gemm_fallback<<<dim3(32, 256), 256, 0, stream>>>(protein, drug, Wv_p, Wv_d, out);
  }
}